// Round 8
// baseline (826.400 us; speedup 1.0000x reference)
//
#include <hip/hip_runtime.h>
#include <cstdint>

// Seq2Seq GRU enc/dec with attention, batch=1, L=50, H=1024, T=128 (fp32).
// Persistent cooperative kernel, 256 WGs x 256 threads.
// Sync via VALUE TAGS (low 5 mantissa bits = step epoch); consumer retry
// loads ARE the poll. Decoder is ONE hop per step: every producer WG
// redundantly computes attn softmax + full o locally (L2-streamed MT).
// gh/enc weights pinned in VGPRs (96 regs); dec_Wih streamed (VGPR<256,
// cooperative-launch occupancy check rejects >256). Fallback normal launch.

#define HDIM 1024
#define LSEQ 50
#define TDIM 128
#define G3   3072
#define PB   6
#define NPROD 128
#define LSTR 68

typedef float f32x4 __attribute__((ext_vector_type(4)));

struct KArgs {
  const int* input_ids; const int* tag_ids;
  const float* word_embed;
  const float* enc_Wih; const float* enc_Whh; const float* enc_bih; const float* enc_bhh;
  const float* dec_embed; const float* attn_W; const float* attn_b;
  const float* comb_W; const float* comb_b;
  const float* dec_Wih; const float* dec_Whh; const float* dec_bih; const float* dec_bhh;
  const float* out_W; const float* out_b;
  float* out;
  unsigned* ctrP; unsigned* ctrE; unsigned* ctrM; unsigned* ctrO; unsigned* ctrV;
  float* hbE;      // 2*1024 tagged
  float* hbD;      // 3*1024 tagged
  float* logits;   // 2*128  tagged
  float* GI;       // 50*3072
  float* attn_e;   // 50*50
  float* pre_comb; // 50*1024
  float* MT;       // 50*1024  (MT[s*H+i])
  float* enc_outs; // 50*1024
};

__device__ __forceinline__ void fence_vm(){
  asm volatile("s_waitcnt vmcnt(0)" ::: "memory");
}
__device__ __forceinline__ void st_coh(float* p, float v){
  __hip_atomic_store(p, v, __ATOMIC_RELAXED, __HIP_MEMORY_SCOPE_AGENT);
}
__device__ __forceinline__ void st_tag(float* p, float v, unsigned tag){
  unsigned b = (__float_as_uint(v) & ~31u) | tag;
  st_coh(p, __uint_as_float(b));
}
__device__ __forceinline__ void stf(unsigned* p, unsigned v){
  __hip_atomic_store(p, v, __ATOMIC_RELAXED, __HIP_MEMORY_SCOPE_AGENT);
}
__device__ __forceinline__ unsigned ldu(const unsigned* p){
  return __hip_atomic_load(p, __ATOMIC_RELAXED, __HIP_MEMORY_SCOPE_AGENT);
}
__device__ __forceinline__ void addc(unsigned* base, int bid){
  __hip_atomic_fetch_add(base + (bid&7)*16, 1u, __ATOMIC_RELAXED, __HIP_MEMORY_SCOPE_AGENT);
}
__device__ __forceinline__ void addc0(unsigned* base){
  __hip_atomic_fetch_add(base, 1u, __ATOMIC_RELAXED, __HIP_MEMORY_SCOPE_AGENT);
}
__device__ __forceinline__ f32x4 coh_load4(const float* p){
  f32x4 v;
  asm volatile("global_load_dwordx4 %0, %1, off sc0 sc1\n\ts_waitcnt vmcnt(0)"
               : "=v"(v) : "v"(p) : "memory");
  return v;
}

template<int N>
__device__ __forceinline__ void wred_batch(float* v){
  #pragma unroll
  for(int o=32;o>0;o>>=1){
    #pragma unroll
    for(int i=0;i<N;i++) v[i] += __shfl_xor(v[i],o,64);
  }
}
__device__ __forceinline__ float wred_sum(float v){
  #pragma unroll
  for(int o=32;o>0;o>>=1) v += __shfl_xor(v,o,64);
  return v;
}
__device__ __forceinline__ float wred_max(float v){
  #pragma unroll
  for(int o=32;o>0;o>>=1) v = fmaxf(v,__shfl_xor(v,o,64));
  return v;
}

struct Chunk { f32x4 a,b,c,d; };
__device__ __forceinline__ Chunk load_chunk(const float* __restrict__ row, int lane){
  const f32x4* p = reinterpret_cast<const f32x4*>(row) + lane*4;
  Chunk w; w.a=p[0]; w.b=p[1]; w.c=p[2]; w.d=p[3]; return w;
}
// pin chunk into VGPRs: opaque asm redefinition prevents rematerialized loads
__device__ __forceinline__ void pin(Chunk& c){
  asm volatile("" : "+v"(c.a), "+v"(c.b), "+v"(c.c), "+v"(c.d));
}
__device__ __forceinline__ float chunk_dot(const Chunk& w, const float* hc){
  return w.a.x*hc[0]+w.a.y*hc[1]+w.a.z*hc[2]+w.a.w*hc[3]
       + w.b.x*hc[4]+w.b.y*hc[5]+w.b.z*hc[6]+w.b.w*hc[7]
       + w.c.x*hc[8]+w.c.y*hc[9]+w.c.z*hc[10]+w.c.w*hc[11]
       + w.d.x*hc[12]+w.d.y*hc[13]+w.d.z*hc[14]+w.d.w*hc[15];
}
__device__ __forceinline__ void load_vec16(const float* __restrict__ v, float* hc, int lane){
  const f32x4* p = reinterpret_cast<const f32x4*>(v) + lane*4;
  f32x4 x0=p[0],x1=p[1],x2=p[2],x3=p[3];
  hc[0]=x0.x; hc[1]=x0.y; hc[2]=x0.z; hc[3]=x0.w;
  hc[4]=x1.x; hc[5]=x1.y; hc[6]=x1.z; hc[7]=x1.w;
  hc[8]=x2.x; hc[9]=x2.y; hc[10]=x2.z; hc[11]=x2.w;
  hc[12]=x3.x; hc[13]=x3.y; hc[14]=x3.z; hc[15]=x3.w;
}
__device__ __forceinline__ float sigm(float x){ return 1.f/(1.f+expf(-x)); }

// retry-stage 1024 tagged floats into transposed LDS; element j at
// lds[(j&15)*LSTR + (j>>4)]; per-thread retry until all 4 tags match.
template<int SLP>
__device__ __forceinline__ void stage_tag(float* ldsb, const float* g, int tid, unsigned tag){
  const float* p = g + 4*tid;
  f32x4 v;
  for(;;){
    v = coh_load4(p);
    unsigned m = ((__float_as_uint(v.x)&31u)^tag) | ((__float_as_uint(v.y)&31u)^tag)
               | ((__float_as_uint(v.z)&31u)^tag) | ((__float_as_uint(v.w)&31u)^tag);
    if(m==0u) break;
    if(SLP) __builtin_amdgcn_s_sleep(SLP);
  }
  int q = tid>>2, r4 = (tid&3)*4;
  ldsb[(r4+0)*LSTR+q]=v.x; ldsb[(r4+1)*LSTR+q]=v.y;
  ldsb[(r4+2)*LSTR+q]=v.z; ldsb[(r4+3)*LSTR+q]=v.w;
}
__device__ __forceinline__ void read16(const float* ldsb, float* hc, int lane){
  #pragma unroll
  for(int k=0;k<16;k++) hc[k]=ldsb[k*LSTR+lane];
}

__device__ __forceinline__ void wait8(const unsigned* base, unsigned n, int lane){
  const unsigned* p = base + lane*16;
  for(;;){
    unsigned v = (lane<8)? ldu(p) : 0xFFFFFFFFu;
    if(__all((int)(v>=n))) return;
    __builtin_amdgcn_s_sleep(8);
  }
}

__global__ __launch_bounds__(256,1) void seq2seq_kernel(KArgs A){
  const int bid = blockIdx.x, tid = threadIdx.x;
  const int wave = tid>>6, lane = tid&63;
  __shared__ float lds_h[16*LSTR+16];
  __shared__ float lds_o[16*LSTR+16];
  __shared__ float smr[64];
  __shared__ float smL[TDIM];
  __shared__ float awL[64];

  const int gv = bid*4 + wave;   // 0..1023

  // ================= prologue: token-dependent precompute ====================
  {
    const int r0 = gv*3;
    Chunk w0 = load_chunk(A.enc_Wih + (size_t)r0*HDIM, lane);
    Chunk w1 = load_chunk(A.enc_Wih + (size_t)(r0+1)*HDIM, lane);
    Chunk w2 = load_chunk(A.enc_Wih + (size_t)(r0+2)*HDIM, lane);
    float b0=A.enc_bih[r0], b1=A.enc_bih[r0+1], b2=A.enc_bih[r0+2];
    for(int te=0;te<LSEQ;++te){
      int tok = A.input_ids[te];
      float ec[16]; load_vec16(A.word_embed + (size_t)tok*HDIM, ec, lane);
      float d[3];
      d[0]=chunk_dot(w0,ec); d[1]=chunk_dot(w1,ec); d[2]=chunk_dot(w2,ec);
      wred_batch<3>(d);
      if(lane==0){
        st_coh(&A.GI[te*G3+r0],   d[0]+b0);
        st_coh(&A.GI[te*G3+r0+1], d[1]+b1);
        st_coh(&A.GI[te*G3+r0+2], d[2]+b2);
      }
    }
    Chunk wc = load_chunk(A.comb_W + (size_t)gv*2*HDIM, lane);
    float bc = A.comb_b[gv];
    Chunk wa; wa.a=0.f; wa.b=0.f; wa.c=0.f; wa.d=0.f;
    float ba = 0.f;
    if(gv < LSEQ){ wa = load_chunk(A.attn_W + (size_t)gv*2*HDIM, lane); ba = A.attn_b[gv]; }
    for(int t=0;t<LSEQ;++t){
      int tok = (t==0)?1:A.tag_ids[t-1];
      float ec[16]; load_vec16(A.dec_embed + (size_t)tok*HDIM, ec, lane);
      float d[2];
      d[0]=chunk_dot(wc,ec);
      d[1]=(gv<LSEQ)? chunk_dot(wa,ec) : 0.f;
      wred_batch<2>(d);
      if(lane==0){
        st_coh(&A.pre_comb[t*HDIM+gv], d[0]+bc);
        if(gv<LSEQ) st_coh(&A.attn_e[t*LSEQ+gv], d[1]+ba);
      }
    }
  }
  fence_vm();
  __syncthreads();
  if(tid==0) addc(A.ctrP, bid);
  if(wave==0) wait8(A.ctrP, 32u, lane);
  __syncthreads();

  // producer geometry: bids 6..133 own 8 h-elements each
  const int p = bid - PB;
  const bool is_prod = (p>=0 && p<NPROD);
  const int base = is_prod ? p*8 : 0;
  const int j8 = base + (tid&7);

  // ================= encoder: 50 sequential GRU steps (producers) ===========
  if(is_prod){
    Chunk we[6];
    #pragma unroll
    for(int i=0;i<6;i++){
      int r = wave + 4*i;                 // 0..23 ; r = 3*le + g
      int le=r/3, g=r-3*le, row=g*HDIM+base+le;
      we[i] = load_chunk(A.enc_Whh + (size_t)row*HDIM, lane);
      pin(we[i]);
    }
    float bh0=A.enc_bhh[j8], bh1=A.enc_bhh[HDIM+j8], bh2=A.enc_bhh[2*HDIM+j8];
    for(int te=0;te<LSEQ;++te){
      const float* GIr = A.GI + te*G3;
      float gi0=GIr[j8], gi1=GIr[HDIM+j8], gi2=GIr[2*HDIM+j8];
      float hc[16];
      if(te>0){
        stage_tag<1>(lds_h, A.hbE + ((te-1)&1)*HDIM, tid, (unsigned)(te&31));
        __syncthreads();
        read16(lds_h, hc, lane);
      } else {
        for(int k=0;k<16;k++) hc[k]=0.f;
      }
      float part[6];
      #pragma unroll
      for(int i=0;i<6;i++) part[i]=chunk_dot(we[i],hc);
      wred_batch<6>(part);
      if(lane==0){
        #pragma unroll
        for(int i=0;i<6;i++) smr[wave+4*i]=part[i];
      }
      __syncthreads();
      if(tid<8){
        int j = base+tid;
        float gr=smr[tid*3]+bh0, gz=smr[tid*3+1]+bh1, gn=smr[tid*3+2]+bh2;
        float hj = (te>0)? lds_h[((j&15)*LSTR)+(j>>4)] : 0.f;
        float r_=sigm(gi0+gr), z_=sigm(gi1+gz);
        float n_=tanhf(gi2+r_*gn);
        float h2=(1.f-z_)*n_+z_*hj;
        st_tag(&A.hbE[(te&1)*HDIM+j], h2, (unsigned)((te+1)&31));
        st_coh(&A.enc_outs[te*HDIM+j], h2);
        if(te==LSEQ-1) st_tag(&A.hbD[j], h2, 0u);
      }
      __syncthreads();
    }
    fence_vm();
    __syncthreads();
    if(tid==0) addc(A.ctrE, bid);
  }
  if(wave==0) wait8(A.ctrE, 16u, lane);   // 128 producers -> 16 per class
  __syncthreads();

  // ================= MT = comb_W[:,H:] @ enc_outs^T ==========================
  {
    Chunk wm = load_chunk(A.comb_W + (size_t)gv*2*HDIM + HDIM, lane);
    for(int sg=0;sg<10;++sg){
      float pt[5];
      #pragma unroll
      for(int j=0;j<5;j++){
        float ec[16]; load_vec16(A.enc_outs + (sg*5+j)*HDIM, ec, lane);
        pt[j]=chunk_dot(wm,ec);
      }
      wred_batch<5>(pt);
      if(lane==0){
        #pragma unroll
        for(int j=0;j<5;j++) st_coh(&A.MT[(sg*5+j)*HDIM+gv], pt[j]);
      }
    }
  }
  fence_vm();
  __syncthreads();
  if(tid==0) addc(A.ctrM, bid);
  if(!is_prod && bid!=4 && !(bid>=134 && bid<150)) return;  // spectators done
  if(wave==0) wait8(A.ctrM, 32u, lane);
  __syncthreads();

  // ================= decoder: 50 steps, ONE hop per step =====================
  if(bid == 4){
    // collect tagged logits, double log_softmax, out + loss
    float loss = 0.f;
    for(int t=0;t<LSEQ;++t){
      if(tid<32){
        const float* pp = A.logits + (t&1)*TDIM + 4*tid;
        const unsigned tg = (unsigned)(t&31);
        f32x4 v;
        for(;;){
          v = coh_load4(pp);
          unsigned m = ((__float_as_uint(v.x)&31u)^tg) | ((__float_as_uint(v.y)&31u)^tg)
                     | ((__float_as_uint(v.z)&31u)^tg) | ((__float_as_uint(v.w)&31u)^tg);
          if(m==0u) break;
          __builtin_amdgcn_s_sleep(1);
        }
        smL[4*tid]=v.x; smL[4*tid+1]=v.y; smL[4*tid+2]=v.z; smL[4*tid+3]=v.w;
      }
      __syncthreads();
      if(tid==0) stf(A.ctrV, (unsigned)(t+1));   // epoch t logits consumed
      if(wave==0){
        float l0=smL[lane], l1=smL[lane+64];
        float m  = wred_max(fmaxf(l0,l1));
        float pe = expf(l0-m)+expf(l1-m);
        float s1 = wred_sum(pe);
        float lse = m + logf(s1);
        float lp0 = l0-lse, lp1 = l1-lse;
        float m2  = wred_max(fmaxf(lp0,lp1));
        float p2  = expf(lp0-m2)+expf(lp1-m2);
        float s2  = wred_sum(p2);
        float lse2 = m2 + logf(s2);
        A.out[t*TDIM + lane]      = lp0;
        A.out[t*TDIM + 64 + lane] = lp1;
        int tg2 = A.tag_ids[t];
        float c = ((lane==tg2)?(lse2-lp0):0.f) + ((lane+64==tg2)?(lse2-lp1):0.f);
        c = wred_sum(c);
        if(tg2 != 0) loss += c;
      }
      __syncthreads();
    }
    if(tid==0) A.out[LSEQ*TDIM] = loss;
  } else if(is_prod){
    // producers: everything local after the h broadcast
    Chunk wh[6];
    int riw[6];
    #pragma unroll
    for(int i=0;i<6;i++){
      int r = wave + 4*i;
      int le=r/3, g=r-3*le, row=g*HDIM+base+le;
      wh[i] = load_chunk(A.dec_Whh + (size_t)row*HDIM, lane);
      pin(wh[i]);
      riw[i] = row;                      // dec_Wih rows streamed at use
    }
    float dh0=A.dec_bhh[j8], dh1=A.dec_bhh[HDIM+j8], dh2=A.dec_bhh[2*HDIM+j8];
    float di0=A.dec_bih[j8], di1=A.dec_bih[HDIM+j8], di2=A.dec_bih[2*HDIM+j8];
    const f32x4* MT4 = reinterpret_cast<const f32x4*>(A.MT);
    const f32x4* PC4 = reinterpret_cast<const f32x4*>(A.pre_comb);
    for(int t=0;t<LSEQ;++t){
      // prefetch step-static data (independent of h)
      f32x4 pc = PC4[t*256+tid];
      float ae[13];
      #pragma unroll
      for(int i=0;i<13;i++){
        int s = (i<7)? wave+4*i : wave+28+4*(i-7);
        ae[i] = (s<LSEQ)? A.attn_e[t*LSEQ+s] : 0.f;
      }
      stage_tag<1>(lds_h, A.hbD + (t%3)*HDIM, tid, (unsigned)(t&31));
      __syncthreads();
      float hc[16]; read16(lds_h, hc, lane);
      // gh dots (pinned VGPR weights)
      float ph[6];
      #pragma unroll
      for(int i=0;i<6;i++) ph[i]=chunk_dot(wh[i],hc);
      wred_batch<6>(ph);
      if(lane==0){
        #pragma unroll
        for(int i=0;i<6;i++) smr[wave+4*i]=ph[i];
      }
      // attn logits (L2-streamed rows)
      {
        float p7[7];
        #pragma unroll
        for(int i=0;i<7;i++){
          int s=wave+4*i;
          Chunk w=load_chunk(A.attn_W+(size_t)s*2*HDIM+HDIM,lane);
          p7[i]=chunk_dot(w,hc);
        }
        wred_batch<7>(p7);
        if(lane==0){
          #pragma unroll
          for(int i=0;i<7;i++) smL[wave+4*i]=p7[i]+ae[i];
        }
        float p6[6];
        #pragma unroll
        for(int i=0;i<6;i++){
          int s=wave+28+4*i; int sc=(s<LSEQ)?s:0;
          Chunk w=load_chunk(A.attn_W+(size_t)sc*2*HDIM+HDIM,lane);
          p6[i]=chunk_dot(w,hc);
        }
        wred_batch<6>(p6);
        if(lane==0){
          #pragma unroll
          for(int i=0;i<6;i++){ int s=wave+28+4*i; if(s<LSEQ) smL[s]=p6[i]+ae[7+i]; }
        }
      }
      __syncthreads();
      if(wave==0){
        float l = (lane<LSEQ)? smL[lane] : -1e30f;
        float m = wred_max(l);
        float pe = (lane<LSEQ)? expf(l-m) : 0.f;
        float ss = wred_sum(pe);
        awL[lane] = (lane<LSEQ)? pe/ss : 0.f;
      }
      __syncthreads();
      // full o locally: o[4t..4t+3] = relu(pc + sum_s MT[s]*aw[s])
      {
        float ox=pc.x, oy=pc.y, oz=pc.z, ow=pc.w;
        #pragma unroll 10
        for(int s=0;s<LSEQ;++s){
          f32x4 m4 = MT4[s*256+tid];
          float a = awL[s];
          ox = fmaf(m4.x,a,ox); oy = fmaf(m4.y,a,oy);
          oz = fmaf(m4.z,a,oz); ow = fmaf(m4.w,a,ow);
        }
        int q=tid>>2, r4=(tid&3)*4;
        lds_o[(r4+0)*LSTR+q]=fmaxf(ox,0.f); lds_o[(r4+1)*LSTR+q]=fmaxf(oy,0.f);
        lds_o[(r4+2)*LSTR+q]=fmaxf(oz,0.f); lds_o[(r4+3)*LSTR+q]=fmaxf(ow,0.f);
      }
      // gate: out-proj WGs must have staged epoch t-2 before we clobber hbD
      if(wave==0 && t>=3){
        const unsigned tgt = 16u*(unsigned)(t-2);
        for(;;){
          unsigned v = (lane==0)? ldu(A.ctrO) : tgt;
          if(__all((int)(v>=tgt))) break;
          __builtin_amdgcn_s_sleep(2);
        }
      }
      __syncthreads();
      float oc[16]; read16(lds_o, oc, lane);
      float po[6];
      #pragma unroll
      for(int i=0;i<6;i++){
        Chunk w = load_chunk(A.dec_Wih + (size_t)riw[i]*HDIM, lane);
        po[i]=chunk_dot(w,oc);
      }
      wred_batch<6>(po);
      if(lane==0){
        #pragma unroll
        for(int i=0;i<6;i++) smr[32+wave+4*i]=po[i];
      }
      __syncthreads();
      if(tid<8){
        int j = base+tid;
        float gr=smr[tid*3]+dh0,    gz=smr[tid*3+1]+dh1,    gn=smr[tid*3+2]+dh2;
        float ir=smr[32+tid*3]+di0, iz=smr[32+tid*3+1]+di1, inn=smr[32+tid*3+2]+di2;
        float hj = lds_h[((j&15)*LSTR)+(j>>4)];
        float r_=sigm(ir+gr), z_=sigm(iz+gz);
        float n_=tanhf(inn+r_*gn);
        float h2=(1.f-z_)*n_+z_*hj;
        st_tag(&A.hbD[((t+1)%3)*HDIM+j], h2, (unsigned)((t+1)&31));
      }
      __syncthreads();
    }
  } else {
    // out-proj: bids 134..149, 8 rows each, 2 rows/wave pinned in VGPRs
    const int ob = bid-134;
    Chunk wo[2];
    float bo[2];
    #pragma unroll
    for(int i=0;i<2;i++){
      int row = ob*8 + wave*2 + i;
      wo[i]=load_chunk(A.out_W+(size_t)row*HDIM,lane);
      pin(wo[i]);
      bo[i]=A.out_b[row];
    }
    for(int t=0;t<LSEQ;++t){
      stage_tag<2>(lds_h, A.hbD + ((t+1)%3)*HDIM, tid, (unsigned)((t+1)&31));
      __syncthreads();
      if(tid==0) addc0(A.ctrO);            // "I staged epoch t+1"
      float hc[16]; read16(lds_h, hc, lane);
      float pt[2]={chunk_dot(wo[0],hc),chunk_dot(wo[1],hc)};
      wred_batch<2>(pt);
      if(wave==0 && t>=2){
        const unsigned tgt = (unsigned)(t-1);  // WG4 consumed epoch t-2
        for(;;){
          unsigned v = (lane==0)? ldu(A.ctrV) : tgt;
          if(__all((int)(v>=tgt))) break;
          __builtin_amdgcn_s_sleep(4);
        }
      }
      __syncthreads();
      if(lane==0){
        int row = ob*8 + wave*2;
        st_tag(&A.logits[(t&1)*TDIM + row],   pt[0]+bo[0], (unsigned)(t&31));
        st_tag(&A.logits[(t&1)*TDIM + row+1], pt[1]+bo[1], (unsigned)(t&31));
      }
      __syncthreads();
    }
  }
}

extern "C" void kernel_launch(void* const* d_in, const int* in_sizes, int n_in,
                              void* d_out, int out_size, void* d_ws, size_t ws_size,
                              hipStream_t stream){
  (void)in_sizes; (void)n_in; (void)out_size; (void)ws_size;
  KArgs A;
  A.input_ids = (const int*)d_in[0];
  A.tag_ids   = (const int*)d_in[1];
  A.word_embed= (const float*)d_in[2];
  A.enc_Wih   = (const float*)d_in[3];
  A.enc_Whh   = (const float*)d_in[4];
  A.enc_bih   = (const float*)d_in[5];
  A.enc_bhh   = (const float*)d_in[6];
  A.dec_embed = (const float*)d_in[7];
  A.attn_W    = (const float*)d_in[8];
  A.attn_b    = (const float*)d_in[9];
  A.comb_W    = (const float*)d_in[10];
  A.comb_b    = (const float*)d_in[11];
  A.dec_Wih   = (const float*)d_in[12];
  A.dec_Whh   = (const float*)d_in[13];
  A.dec_bih   = (const float*)d_in[14];
  A.dec_bhh   = (const float*)d_in[15];
  A.out_W     = (const float*)d_in[16];
  A.out_b     = (const float*)d_in[17];
  A.out       = (float*)d_out;

  unsigned* u = (unsigned*)d_ws;
  A.ctrP = u;          // 8 lines (stride 16u)
  A.ctrE = u + 128;
  A.ctrM = u + 256;
  A.ctrO = u + 384;    // single line
  A.ctrV = u + 448;    // single line
  float* f = (float*)d_ws + 1024;   // byte 4096
  A.hbE    = f; f += 2*HDIM;        // tagged region start
  A.hbD    = f; f += 3*HDIM;
  A.logits = f; f += 2*TDIM;        // tagged region: 5376 floats
  A.GI       = f; f += LSEQ*G3;
  A.attn_e   = f; f += LSEQ*LSEQ + 14;
  A.pre_comb = f; f += LSEQ*HDIM;
  A.MT       = f; f += LSEQ*HDIM;
  A.enc_outs = f; f += LSEQ*HDIM;

  (void)hipMemsetAsync(d_ws, 0, 4096, stream);                        // counters
  (void)hipMemsetAsync((char*)d_ws + 4096, 0xFF, 5376*4, stream);     // tag bufs -> tag 31
  void* args[] = { &A };
  hipError_t err = hipLaunchCooperativeKernel((const void*)seq2seq_kernel,
                                              dim3(256), dim3(256), args, 0, stream);
  if(err != hipSuccess){
    // 256 WGs on 256 CUs are co-resident by capacity; cooperative API was
    // only belt-and-braces. Fall back to a normal launch.
    hipLaunchKernelGGL(seq2seq_kernel, dim3(256), dim3(256), 0, stream, A);
  }
}

// Round 9
// 561.191 us; speedup vs baseline: 1.4726x; 1.4726x over previous
//
#include <hip/hip_runtime.h>
#include <cstdint>

// Seq2Seq GRU enc/dec with attention, batch=1, L=50, H=1024, T=128 (fp32).
// Persistent cooperative kernel, 256 WGs x 256 threads.
// Sync via VALUE TAGS (low 5 mantissa bits = epoch); consumer retry loads
// ARE the poll. Decoder pipeline: h -> WG0 (pinned attn rows -> aw, 52-float
// broadcast) -> o-WGs (pinned 50 M-coeffs/thread -> o) -> producers (pinned
// wh+wi -> h'). All critical-path weights register-resident.

#define HDIM 1024
#define LSEQ 50
#define TDIM 128
#define G3   3072
#define PB   6
#define NPROD 128
#define LSTR 68

typedef float f32x4 __attribute__((ext_vector_type(4)));

struct KArgs {
  const int* input_ids; const int* tag_ids;
  const float* word_embed;
  const float* enc_Wih; const float* enc_Whh; const float* enc_bih; const float* enc_bhh;
  const float* dec_embed; const float* attn_W; const float* attn_b;
  const float* comb_W; const float* comb_b;
  const float* dec_Wih; const float* dec_Whh; const float* dec_bih; const float* dec_bhh;
  const float* out_W; const float* out_b;
  float* out;
  unsigned* ctrP; unsigned* ctrE; unsigned* ctrM; unsigned* ctrO; unsigned* ctrV;
  float* hbE;      // 2*1024 tagged
  float* hbD;      // 3*1024 tagged
  float* obD;      // 2*1024 tagged
  float* awb;      // 2*64   tagged (52 used)
  float* logits;   // 2*128  tagged
  float* GI;       // 50*3072
  float* attn_e;   // 50*50
  float* pre_comb; // 50*1024
  float* MT;       // 50*1024  (MT[s*H+i])
  float* enc_outs; // 50*1024
};

__device__ __forceinline__ void fence_vm(){
  asm volatile("s_waitcnt vmcnt(0)" ::: "memory");
}
__device__ __forceinline__ void st_coh(float* p, float v){
  __hip_atomic_store(p, v, __ATOMIC_RELAXED, __HIP_MEMORY_SCOPE_AGENT);
}
__device__ __forceinline__ void st_tag(float* p, float v, unsigned tag){
  unsigned b = (__float_as_uint(v) & ~31u) | tag;
  st_coh(p, __uint_as_float(b));
}
__device__ __forceinline__ void stf(unsigned* p, unsigned v){
  __hip_atomic_store(p, v, __ATOMIC_RELAXED, __HIP_MEMORY_SCOPE_AGENT);
}
__device__ __forceinline__ unsigned ldu(const unsigned* p){
  return __hip_atomic_load(p, __ATOMIC_RELAXED, __HIP_MEMORY_SCOPE_AGENT);
}
__device__ __forceinline__ void addc(unsigned* base, int bid){
  __hip_atomic_fetch_add(base + (bid&7)*16, 1u, __ATOMIC_RELAXED, __HIP_MEMORY_SCOPE_AGENT);
}
__device__ __forceinline__ void addc0(unsigned* base){
  __hip_atomic_fetch_add(base, 1u, __ATOMIC_RELAXED, __HIP_MEMORY_SCOPE_AGENT);
}
__device__ __forceinline__ f32x4 coh_load4(const float* p){
  f32x4 v;
  asm volatile("global_load_dwordx4 %0, %1, off sc0 sc1\n\ts_waitcnt vmcnt(0)"
               : "=v"(v) : "v"(p) : "memory");
  return v;
}

template<int N>
__device__ __forceinline__ void wred_batch(float* v){
  #pragma unroll
  for(int o=32;o>0;o>>=1){
    #pragma unroll
    for(int i=0;i<N;i++) v[i] += __shfl_xor(v[i],o,64);
  }
}
__device__ __forceinline__ float wred_sum(float v){
  #pragma unroll
  for(int o=32;o>0;o>>=1) v += __shfl_xor(v,o,64);
  return v;
}
__device__ __forceinline__ float wred_max(float v){
  #pragma unroll
  for(int o=32;o>0;o>>=1) v = fmaxf(v,__shfl_xor(v,o,64));
  return v;
}

struct Chunk { f32x4 a,b,c,d; };
__device__ __forceinline__ Chunk load_chunk(const float* __restrict__ row, int lane){
  const f32x4* p = reinterpret_cast<const f32x4*>(row) + lane*4;
  Chunk w; w.a=p[0]; w.b=p[1]; w.c=p[2]; w.d=p[3]; return w;
}
__device__ __forceinline__ void pin(Chunk& c){
  asm volatile("" : "+v"(c.a), "+v"(c.b), "+v"(c.c), "+v"(c.d));
}
__device__ __forceinline__ void pinf(float& x){
  asm volatile("" : "+v"(x));
}
__device__ __forceinline__ float chunk_dot(const Chunk& w, const float* hc){
  return w.a.x*hc[0]+w.a.y*hc[1]+w.a.z*hc[2]+w.a.w*hc[3]
       + w.b.x*hc[4]+w.b.y*hc[5]+w.b.z*hc[6]+w.b.w*hc[7]
       + w.c.x*hc[8]+w.c.y*hc[9]+w.c.z*hc[10]+w.c.w*hc[11]
       + w.d.x*hc[12]+w.d.y*hc[13]+w.d.z*hc[14]+w.d.w*hc[15];
}
__device__ __forceinline__ void load_vec16(const float* __restrict__ v, float* hc, int lane){
  const f32x4* p = reinterpret_cast<const f32x4*>(v) + lane*4;
  f32x4 x0=p[0],x1=p[1],x2=p[2],x3=p[3];
  hc[0]=x0.x; hc[1]=x0.y; hc[2]=x0.z; hc[3]=x0.w;
  hc[4]=x1.x; hc[5]=x1.y; hc[6]=x1.z; hc[7]=x1.w;
  hc[8]=x2.x; hc[9]=x2.y; hc[10]=x2.z; hc[11]=x2.w;
  hc[12]=x3.x; hc[13]=x3.y; hc[14]=x3.z; hc[15]=x3.w;
}
__device__ __forceinline__ float sigm(float x){ return 1.f/(1.f+expf(-x)); }

// retry-stage 1024 tagged floats into transposed LDS; element j at
// lds[(j&15)*LSTR + (j>>4)]; per-thread retry until all 4 tags match.
template<int SLP>
__device__ __forceinline__ void stage_tag(float* ldsb, const float* g, int tid, unsigned tag){
  const float* p = g + 4*tid;
  f32x4 v;
  for(;;){
    v = coh_load4(p);
    unsigned m = ((__float_as_uint(v.x)&31u)^tag) | ((__float_as_uint(v.y)&31u)^tag)
               | ((__float_as_uint(v.z)&31u)^tag) | ((__float_as_uint(v.w)&31u)^tag);
    if(m==0u) break;
    if(SLP) __builtin_amdgcn_s_sleep(SLP);
  }
  int q = tid>>2, r4 = (tid&3)*4;
  ldsb[(r4+0)*LSTR+q]=v.x; ldsb[(r4+1)*LSTR+q]=v.y;
  ldsb[(r4+2)*LSTR+q]=v.z; ldsb[(r4+3)*LSTR+q]=v.w;
}
__device__ __forceinline__ void read16(const float* ldsb, float* hc, int lane){
  #pragma unroll
  for(int k=0;k<16;k++) hc[k]=ldsb[k*LSTR+lane];
}

__device__ __forceinline__ void wait8(const unsigned* base, unsigned n, int lane){
  const unsigned* p = base + lane*16;
  for(;;){
    unsigned v = (lane<8)? ldu(p) : 0xFFFFFFFFu;
    if(__all((int)(v>=n))) return;
    __builtin_amdgcn_s_sleep(8);
  }
}

__global__ __launch_bounds__(256,1) void seq2seq_kernel(KArgs A){
  const int bid = blockIdx.x, tid = threadIdx.x;
  const int wave = tid>>6, lane = tid&63;
  __shared__ float lds_h[16*LSTR+16];
  __shared__ float lds_o[16*LSTR+16];
  __shared__ float smr[64];
  __shared__ float smL[TDIM];
  __shared__ float smA[64];

  const int gv = bid*4 + wave;   // 0..1023

  // ================= prologue: token-dependent precompute ====================
  {
    const int r0 = gv*3;
    Chunk w0 = load_chunk(A.enc_Wih + (size_t)r0*HDIM, lane);
    Chunk w1 = load_chunk(A.enc_Wih + (size_t)(r0+1)*HDIM, lane);
    Chunk w2 = load_chunk(A.enc_Wih + (size_t)(r0+2)*HDIM, lane);
    float b0=A.enc_bih[r0], b1=A.enc_bih[r0+1], b2=A.enc_bih[r0+2];
    for(int te=0;te<LSEQ;++te){
      int tok = A.input_ids[te];
      float ec[16]; load_vec16(A.word_embed + (size_t)tok*HDIM, ec, lane);
      float d[3];
      d[0]=chunk_dot(w0,ec); d[1]=chunk_dot(w1,ec); d[2]=chunk_dot(w2,ec);
      wred_batch<3>(d);
      if(lane==0){
        st_coh(&A.GI[te*G3+r0],   d[0]+b0);
        st_coh(&A.GI[te*G3+r0+1], d[1]+b1);
        st_coh(&A.GI[te*G3+r0+2], d[2]+b2);
      }
    }
    Chunk wc = load_chunk(A.comb_W + (size_t)gv*2*HDIM, lane);
    float bc = A.comb_b[gv];
    Chunk wa; wa.a=0.f; wa.b=0.f; wa.c=0.f; wa.d=0.f;
    float ba = 0.f;
    if(gv < LSEQ){ wa = load_chunk(A.attn_W + (size_t)gv*2*HDIM, lane); ba = A.attn_b[gv]; }
    for(int t=0;t<LSEQ;++t){
      int tok = (t==0)?1:A.tag_ids[t-1];
      float ec[16]; load_vec16(A.dec_embed + (size_t)tok*HDIM, ec, lane);
      float d[2];
      d[0]=chunk_dot(wc,ec);
      d[1]=(gv<LSEQ)? chunk_dot(wa,ec) : 0.f;
      wred_batch<2>(d);
      if(lane==0){
        st_coh(&A.pre_comb[t*HDIM+gv], d[0]+bc);
        if(gv<LSEQ) st_coh(&A.attn_e[t*LSEQ+gv], d[1]+ba);
      }
    }
  }
  fence_vm();
  __syncthreads();
  if(tid==0) addc(A.ctrP, bid);
  if(wave==0) wait8(A.ctrP, 32u, lane);
  __syncthreads();

  // producer geometry: bids 6..133 own 8 h-elements each
  const int p = bid - PB;
  const bool is_prod = (p>=0 && p<NPROD);
  const int base = is_prod ? p*8 : 0;
  const int j8 = base + (tid&7);

  // ================= encoder: 50 sequential GRU steps (producers) ===========
  if(is_prod){
    Chunk we[6];
    #pragma unroll
    for(int i=0;i<6;i++){
      int r = wave + 4*i;                 // 0..23 ; r = 3*le + g
      int le=r/3, g=r-3*le, row=g*HDIM+base+le;
      we[i] = load_chunk(A.enc_Whh + (size_t)row*HDIM, lane);
      pin(we[i]);
    }
    float bh0=A.enc_bhh[j8], bh1=A.enc_bhh[HDIM+j8], bh2=A.enc_bhh[2*HDIM+j8];
    for(int te=0;te<LSEQ;++te){
      const float* GIr = A.GI + te*G3;
      float gi0=GIr[j8], gi1=GIr[HDIM+j8], gi2=GIr[2*HDIM+j8];
      float hc[16];
      if(te>0){
        stage_tag<1>(lds_h, A.hbE + ((te-1)&1)*HDIM, tid, (unsigned)(te&31));
        __syncthreads();
        read16(lds_h, hc, lane);
      } else {
        for(int k=0;k<16;k++) hc[k]=0.f;
      }
      float part[6];
      #pragma unroll
      for(int i=0;i<6;i++) part[i]=chunk_dot(we[i],hc);
      wred_batch<6>(part);
      if(lane==0){
        #pragma unroll
        for(int i=0;i<6;i++) smr[wave+4*i]=part[i];
      }
      __syncthreads();
      if(tid<8){
        int j = base+tid;
        float gr=smr[tid*3]+bh0, gz=smr[tid*3+1]+bh1, gn=smr[tid*3+2]+bh2;
        float hj = (te>0)? lds_h[((j&15)*LSTR)+(j>>4)] : 0.f;
        float r_=sigm(gi0+gr), z_=sigm(gi1+gz);
        float n_=tanhf(gi2+r_*gn);
        float h2=(1.f-z_)*n_+z_*hj;
        st_tag(&A.hbE[(te&1)*HDIM+j], h2, (unsigned)((te+1)&31));
        st_coh(&A.enc_outs[te*HDIM+j], h2);
        if(te==LSEQ-1) st_tag(&A.hbD[j], h2, 0u);
      }
      __syncthreads();
    }
    fence_vm();
    __syncthreads();
    if(tid==0) addc(A.ctrE, bid);
  }
  if(wave==0) wait8(A.ctrE, 16u, lane);   // 128 producers -> 16 per class
  __syncthreads();

  // ================= MT = comb_W[:,H:] @ enc_outs^T ==========================
  {
    Chunk wm = load_chunk(A.comb_W + (size_t)gv*2*HDIM + HDIM, lane);
    for(int sg=0;sg<10;++sg){
      float pt[5];
      #pragma unroll
      for(int j=0;j<5;j++){
        float ec[16]; load_vec16(A.enc_outs + (sg*5+j)*HDIM, ec, lane);
        pt[j]=chunk_dot(wm,ec);
      }
      wred_batch<5>(pt);
      if(lane==0){
        #pragma unroll
        for(int j=0;j<5;j++) st_coh(&A.MT[(sg*5+j)*HDIM+gv], pt[j]);
      }
    }
  }
  fence_vm();
  __syncthreads();
  if(tid==0) addc(A.ctrM, bid);
  {
    const bool keep = is_prod || bid==0 || bid==4 ||
                      (bid>=134 && bid<154);
    if(!keep) return;                      // spectators done
  }
  if(wave==0) wait8(A.ctrM, 32u, lane);
  __syncthreads();

  // ================= decoder: 50 steps, pipelined specialists ================
  if(bid == 0){
    // attn WG: 13 pinned attn_W[:,H:] chunks per wave (s = wave+4*i)
    Chunk wa13[13];
    int srow[13];
    #pragma unroll
    for(int i=0;i<13;i++){
      int s = wave + 4*i; int sc = (s<LSEQ)? s : 0;
      wa13[i] = load_chunk(A.attn_W + (size_t)sc*2*HDIM + HDIM, lane);
      pin(wa13[i]);
      srow[i] = s;
    }
    for(int t=0;t<LSEQ;++t){
      float ae[13];
      #pragma unroll
      for(int i=0;i<13;i++)
        ae[i] = (srow[i]<LSEQ)? A.attn_e[t*LSEQ+srow[i]] : 0.f;
      stage_tag<1>(lds_h, A.hbD + (t%3)*HDIM, tid, (unsigned)(t&31));
      __syncthreads();
      float hc[16]; read16(lds_h, hc, lane);
      float pl[13];
      #pragma unroll
      for(int i=0;i<13;i++) pl[i]=chunk_dot(wa13[i],hc);
      wred_batch<13>(pl);
      if(lane==0){
        #pragma unroll
        for(int i=0;i<13;i++) if(srow[i]<LSEQ) smL[srow[i]]=pl[i]+ae[i];
      }
      __syncthreads();
      if(wave==0){
        float l = (lane<LSEQ)? smL[lane] : -1e30f;
        float m = wred_max(l);
        float pe = (lane<LSEQ)? expf(l-m) : 0.f;
        float ss = wred_sum(pe);
        float av = (lane<LSEQ)? pe/ss : 0.f;
        if(lane<52) st_tag(&A.awb[(t&1)*64+lane], av, (unsigned)(t&31));
      }
      __syncthreads();
    }
  } else if(bid>=150 && bid<154){
    // o-WGs: thread owns o[i]; 50 M coefficients pinned in VGPRs
    const int i = (bid-150)*256 + tid;
    float m50[50];
    #pragma unroll
    for(int s=0;s<LSEQ;s++){ m50[s]=A.MT[s*HDIM+i]; pinf(m50[s]); }
    for(int t=0;t<LSEQ;++t){
      float pcv = A.pre_comb[t*HDIM+i];
      if(tid<13){
        const float* pp = A.awb + (t&1)*64 + 4*tid;
        const unsigned tg = (unsigned)(t&31);
        f32x4 v;
        for(;;){
          v = coh_load4(pp);
          unsigned m = ((__float_as_uint(v.x)&31u)^tg) | ((__float_as_uint(v.y)&31u)^tg)
                     | ((__float_as_uint(v.z)&31u)^tg) | ((__float_as_uint(v.w)&31u)^tg);
          if(m==0u) break;
        }
        smA[4*tid]=v.x; smA[4*tid+1]=v.y; smA[4*tid+2]=v.z; smA[4*tid+3]=v.w;
      }
      __syncthreads();
      float acc = pcv;
      #pragma unroll
      for(int s=0;s<LSEQ;s++) acc = fmaf(m50[s], smA[s], acc);
      st_tag(&A.obD[(t&1)*HDIM+i], fmaxf(acc,0.f), (unsigned)(t&31));
      __syncthreads();
    }
  } else if(bid == 4){
    // collect tagged logits, double log_softmax, out + loss
    float loss = 0.f;
    for(int t=0;t<LSEQ;++t){
      if(tid<32){
        const float* pp = A.logits + (t&1)*TDIM + 4*tid;
        const unsigned tg = (unsigned)(t&31);
        f32x4 v;
        for(;;){
          v = coh_load4(pp);
          unsigned m = ((__float_as_uint(v.x)&31u)^tg) | ((__float_as_uint(v.y)&31u)^tg)
                     | ((__float_as_uint(v.z)&31u)^tg) | ((__float_as_uint(v.w)&31u)^tg);
          if(m==0u) break;
          __builtin_amdgcn_s_sleep(1);
        }
        smL[4*tid]=v.x; smL[4*tid+1]=v.y; smL[4*tid+2]=v.z; smL[4*tid+3]=v.w;
      }
      __syncthreads();
      if(tid==0) stf(A.ctrV, (unsigned)(t+1));   // epoch t logits consumed
      if(wave==0){
        float l0=smL[lane], l1=smL[lane+64];
        float m  = wred_max(fmaxf(l0,l1));
        float pe = expf(l0-m)+expf(l1-m);
        float s1 = wred_sum(pe);
        float lse = m + logf(s1);
        float lp0 = l0-lse, lp1 = l1-lse;
        float m2  = wred_max(fmaxf(lp0,lp1));
        float p2  = expf(lp0-m2)+expf(lp1-m2);
        float s2  = wred_sum(p2);
        float lse2 = m2 + logf(s2);
        A.out[t*TDIM + lane]      = lp0;
        A.out[t*TDIM + 64 + lane] = lp1;
        int tg2 = A.tag_ids[t];
        float c = ((lane==tg2)?(lse2-lp0):0.f) + ((lane+64==tg2)?(lse2-lp1):0.f);
        c = wred_sum(c);
        if(tg2 != 0) loss += c;
      }
      __syncthreads();
    }
    if(tid==0) A.out[LSEQ*TDIM] = loss;
  } else if(is_prod){
    // producers: pinned wh + wi; stage h -> gh -> stage o -> gi -> combine
    Chunk wh[6], wi[6];
    #pragma unroll
    for(int i=0;i<6;i++){
      int r = wave + 4*i;
      int le=r/3, g=r-3*le, row=g*HDIM+base+le;
      wh[i] = load_chunk(A.dec_Whh + (size_t)row*HDIM, lane);
      pin(wh[i]);
      wi[i] = load_chunk(A.dec_Wih + (size_t)row*HDIM, lane);
      pin(wi[i]);
    }
    float dh0=A.dec_bhh[j8], dh1=A.dec_bhh[HDIM+j8], dh2=A.dec_bhh[2*HDIM+j8];
    float di0=A.dec_bih[j8], di1=A.dec_bih[HDIM+j8], di2=A.dec_bih[2*HDIM+j8];
    for(int t=0;t<LSEQ;++t){
      stage_tag<1>(lds_h, A.hbD + (t%3)*HDIM, tid, (unsigned)(t&31));
      __syncthreads();
      float hc[16]; read16(lds_h, hc, lane);
      float ph[6];
      #pragma unroll
      for(int i=0;i<6;i++) ph[i]=chunk_dot(wh[i],hc);
      wred_batch<6>(ph);
      if(lane==0){
        #pragma unroll
        for(int i=0;i<6;i++) smr[wave+4*i]=ph[i];
      }
      // gate: out-proj WGs must have staged epoch t-2 before we clobber hbD
      if(wave==0 && t>=3){
        const unsigned tgt = 16u*(unsigned)(t-2);
        for(;;){
          unsigned v = (lane==0)? ldu(A.ctrO) : tgt;
          if(__all((int)(v>=tgt))) break;
          __builtin_amdgcn_s_sleep(2);
        }
      }
      stage_tag<1>(lds_o, A.obD + (t&1)*HDIM, tid, (unsigned)(t&31));
      __syncthreads();
      float oc[16]; read16(lds_o, oc, lane);
      float po[6];
      #pragma unroll
      for(int i=0;i<6;i++) po[i]=chunk_dot(wi[i],oc);
      wred_batch<6>(po);
      if(lane==0){
        #pragma unroll
        for(int i=0;i<6;i++) smr[32+wave+4*i]=po[i];
      }
      __syncthreads();
      if(tid<8){
        int j = base+tid;
        float gr=smr[tid*3]+dh0,    gz=smr[tid*3+1]+dh1,    gn=smr[tid*3+2]+dh2;
        float ir=smr[32+tid*3]+di0, iz=smr[32+tid*3+1]+di1, inn=smr[32+tid*3+2]+di2;
        float hj = lds_h[((j&15)*LSTR)+(j>>4)];
        float r_=sigm(ir+gr), z_=sigm(iz+gz);
        float n_=tanhf(inn+r_*gn);
        float h2=(1.f-z_)*n_+z_*hj;
        st_tag(&A.hbD[((t+1)%3)*HDIM+j], h2, (unsigned)((t+1)&31));
      }
      __syncthreads();
    }
  } else {
    // out-proj: bids 134..149, 8 rows each, 2 rows/wave pinned in VGPRs
    const int ob = bid-134;
    Chunk wo[2];
    float bo[2];
    #pragma unroll
    for(int i=0;i<2;i++){
      int row = ob*8 + wave*2 + i;
      wo[i]=load_chunk(A.out_W+(size_t)row*HDIM,lane);
      pin(wo[i]);
      bo[i]=A.out_b[row];
    }
    for(int t=0;t<LSEQ;++t){
      stage_tag<2>(lds_h, A.hbD + ((t+1)%3)*HDIM, tid, (unsigned)((t+1)&31));
      __syncthreads();
      if(tid==0) addc0(A.ctrO);            // "I staged epoch t+1"
      float hc[16]; read16(lds_h, hc, lane);
      float pt[2]={chunk_dot(wo[0],hc),chunk_dot(wo[1],hc)};
      wred_batch<2>(pt);
      if(wave==0 && t>=2){
        const unsigned tgt = (unsigned)(t-1);  // WG4 consumed epoch t-2
        for(;;){
          unsigned v = (lane==0)? ldu(A.ctrV) : tgt;
          if(__all((int)(v>=tgt))) break;
          __builtin_amdgcn_s_sleep(4);
        }
      }
      __syncthreads();
      if(lane==0){
        int row = ob*8 + wave*2;
        st_tag(&A.logits[(t&1)*TDIM + row],   pt[0]+bo[0], (unsigned)(t&31));
        st_tag(&A.logits[(t&1)*TDIM + row+1], pt[1]+bo[1], (unsigned)(t&31));
      }
      __syncthreads();
    }
  }
}

extern "C" void kernel_launch(void* const* d_in, const int* in_sizes, int n_in,
                              void* d_out, int out_size, void* d_ws, size_t ws_size,
                              hipStream_t stream){
  (void)in_sizes; (void)n_in; (void)out_size; (void)ws_size;
  KArgs A;
  A.input_ids = (const int*)d_in[0];
  A.tag_ids   = (const int*)d_in[1];
  A.word_embed= (const float*)d_in[2];
  A.enc_Wih   = (const float*)d_in[3];
  A.enc_Whh   = (const float*)d_in[4];
  A.enc_bih   = (const float*)d_in[5];
  A.enc_bhh   = (const float*)d_in[6];
  A.dec_embed = (const float*)d_in[7];
  A.attn_W    = (const float*)d_in[8];
  A.attn_b    = (const float*)d_in[9];
  A.comb_W    = (const float*)d_in[10];
  A.comb_b    = (const float*)d_in[11];
  A.dec_Wih   = (const float*)d_in[12];
  A.dec_Whh   = (const float*)d_in[13];
  A.dec_bih   = (const float*)d_in[14];
  A.dec_bhh   = (const float*)d_in[15];
  A.out_W     = (const float*)d_in[16];
  A.out_b     = (const float*)d_in[17];
  A.out       = (float*)d_out;

  unsigned* u = (unsigned*)d_ws;
  A.ctrP = u;          // 8 lines (stride 16u)
  A.ctrE = u + 128;
  A.ctrM = u + 256;
  A.ctrO = u + 384;    // single line
  A.ctrV = u + 448;    // single line
  float* f = (float*)d_ws + 1024;   // byte 4096, tagged region start
  A.hbE    = f; f += 2*HDIM;
  A.hbD    = f; f += 3*HDIM;
  A.obD    = f; f += 2*HDIM;
  A.awb    = f; f += 2*64;
  A.logits = f; f += 2*TDIM;        // tagged region: 7552 floats
  A.GI       = f; f += LSEQ*G3;
  A.attn_e   = f; f += LSEQ*LSEQ + 14;
  A.pre_comb = f; f += LSEQ*HDIM;
  A.MT       = f; f += LSEQ*HDIM;
  A.enc_outs = f; f += LSEQ*HDIM;

  (void)hipMemsetAsync(d_ws, 0, 4096, stream);                        // counters
  (void)hipMemsetAsync((char*)d_ws + 4096, 0xFF, 7552*4, stream);     // tag bufs -> tag 31
  void* args[] = { &A };
  hipError_t err = hipLaunchCooperativeKernel((const void*)seq2seq_kernel,
                                              dim3(256), dim3(256), args, 0, stream);
  if(err != hipSuccess){
    // 256 WGs on 256 CUs are co-resident by capacity; cooperative API was
    // only belt-and-braces. Fall back to a normal launch.
    hipLaunchKernelGGL(seq2seq_kernel, dim3(256), dim3(256), 0, stream, A);
  }
}